// Round 9
// baseline (2354150.391 us; speedup 1.0000x reference)
//
#include <hip/hip_runtime.h>
#include <hip/hip_bf16.h>
#include <stdint.h>

// LSTM (T=1024, B=64, D=512, H=512) on gfx950 — FUSED single launch.
// R9 = discrimination experiment:
//   blocks 0..63   : team/LSTM WGs (R4-proven tight agent poll, XCD-local L2
//                    H exchange via per-t history buffer).
//   blocks 64..255 : GEMM producers (X tiles in t-order, sc1 stores, chunk
//                    counters), then HIGH-POWER heaters (16 indep FMA + 2
//                    junk MFMA / iter; LDS done flag).
//   block  256     : CLOCK PROBE — fixed 4.26e9-cycle dependent FMA loop.
//                    dur_us ≈ max(work, probe): ~1.8ms@2.4GHz, ~5.9ms@725MHz.

typedef float    f32x4  __attribute__((ext_vector_type(4)));
typedef short    s16x8  __attribute__((ext_vector_type(8)));
typedef unsigned short u16;
typedef u16      u16x4  __attribute__((ext_vector_type(4)));
typedef unsigned int u32;

#define TT 1024
#define BB 64
#define DD 512
#define HH 512
#define NG 2048
#define NTEAM 8
#define NSLOT 8
#define NTWG 64
#define NGWG 192
#define CHUNK_STEPS 32
#define NCHUNK 32
#define TPC 256
#define NTILES 8192

__device__ __forceinline__ u16 f2bf(float f) {
  __hip_bfloat16 h = __float2bfloat16(f);
  union { __hip_bfloat16 b; u16 u; } v; v.b = h; return v.u;
}
__device__ __forceinline__ float bf2f(u16 u) {
  union { unsigned int i; float f; } v; v.i = ((unsigned int)u) << 16; return v.f;
}
__device__ __forceinline__ float sig_fast(float x) { return 1.f / (1.f + __expf(-x)); }
__device__ __forceinline__ float tanh_fast(float x) { return 1.f - 2.f / (1.f + __expf(2.f * x)); }

__device__ __forceinline__ void gload_lds16(const u16* g, u16* l) {
  __builtin_amdgcn_global_load_lds(
      (const __attribute__((address_space(1))) unsigned int*)g,
      (__attribute__((address_space(3))) unsigned int*)l, 16, 0, 0);
}
__device__ __forceinline__ void st_plain(u32* p, u32 v) {
  asm volatile("global_store_dword %0, %1, off" :: "v"(p), "v"(v) : "memory");
}
__device__ __forceinline__ void st_short_sc1(u16* p, u16 v) {
  asm volatile("global_store_short %0, %1, off sc1" :: "v"(p), "v"((u32)v) : "memory");
}

// ---------------- setup kernels ----------------
__global__ void k_cast(const float* __restrict__ in, u16* __restrict__ out, long n) {
  long i = ((long)blockIdx.x * blockDim.x + threadIdx.x) * 4;
  if (i >= n) return;
  const float4 v = *(const float4*)(in + i);
  u16x4 o; o.x = f2bf(v.x); o.y = f2bf(v.y); o.z = f2bf(v.z); o.w = f2bf(v.w);
  *(u16x4*)(out + i) = o;
}

__global__ void k_pack(const float* __restrict__ Wxi, const float* __restrict__ Whi, const float* __restrict__ bi,
                       const float* __restrict__ Wxf, const float* __restrict__ Whf, const float* __restrict__ bfi,
                       const float* __restrict__ Wxo, const float* __restrict__ Who, const float* __restrict__ bo,
                       const float* __restrict__ Wxc, const float* __restrict__ Whc, const float* __restrict__ bc,
                       u16* __restrict__ WxT, u16* __restrict__ WhT, float* __restrict__ biasp)
{
  const int k = blockIdx.x;
  const float* Wx[4] = {Wxi, Wxf, Wxo, Wxc};
  const float* Wh[4] = {Whi, Whf, Who, Whc};
  for (int h = threadIdx.x; h < HH; h += blockDim.x) {
#pragma unroll
    for (int g = 0; g < 4; ++g) {
      const long n = h * 4 + g;
      WxT[n * DD + k] = f2bf(Wx[g][(long)k * HH + h]);
      WhT[n * HH + k] = f2bf(Wh[g][(long)k * HH + h]);
    }
  }
  if (k == 0) {
    const float* bp[4] = {bi, bfi, bo, bc};
    for (int n = threadIdx.x; n < NG; n += blockDim.x)
      biasp[n] = bp[n & 3][n >> 2];
  }
}

// ---------------- fused kernel ----------------
__global__ __launch_bounds__(512, 2) void k_fused(
    const u16* __restrict__ inbf, const u16* __restrict__ WxT,
    const u16* __restrict__ WhT, const float* __restrict__ biasp,
    u16* __restrict__ X, u16* __restrict__ Hh, float* __restrict__ Cst,
    float* __restrict__ dout, float* __restrict__ doutH, float* __restrict__ doutC,
    u32* __restrict__ ctl, u32* __restrict__ flags, u32* __restrict__ cnt)
{
  __shared__ __align__(16) u16 As[128 * 64];
  __shared__ __align__(16) u16 Bs[128 * 64];
  __shared__ __align__(16) float pre[8][260];
  __shared__ int s_team, s_slot, s_mixed;
  const int tid = threadIdx.x;
  const int role = blockIdx.x;
  const int l = tid & 63, wv = tid >> 6;

  if (role == NTWG + NGWG) {
    // ================= CLOCK PROBE: fixed 4.26e9-cycle dependent FMA =================
    if (wv == 0) {
      float a = 1.0f + (float)l;
      const float m = 1.0000001f, c = 1.0e-7f;
      for (int i = 0; i < 133000000; ++i) {   // 8 dep FMAs x ~4cy = 32 cy/iter
        a = __builtin_fmaf(a, m, c); a = __builtin_fmaf(a, m, c);
        a = __builtin_fmaf(a, m, c); a = __builtin_fmaf(a, m, c);
        a = __builtin_fmaf(a, m, c); a = __builtin_fmaf(a, m, c);
        a = __builtin_fmaf(a, m, c); a = __builtin_fmaf(a, m, c);
      }
      asm volatile("" :: "v"(a));
    }
    return;
  }

  if (role >= NTWG) {
    // ================= GEMM producer + HIGH-POWER heater =================
    const int gwg = role - NTWG;
    const int wr = wv >> 2, wc = wv & 3;
    const int lr = l >> 3, lc = l & 7;
    const int cl = l & 15, rg = l >> 4;

    for (int tile = gwg; tile < NTILES; tile += NGWG) {
      const int c = tile >> 8, q = tile & 255;
      const long brow = (long)(c * 16 + (q >> 4)) * 128;
      const int  bcol = (q & 15) * 128;

      f32x4 acc[4][2];
#pragma unroll
      for (int m = 0; m < 4; ++m)
#pragma unroll
        for (int n = 0; n < 2; ++n) acc[m][n] = (f32x4){0.f, 0.f, 0.f, 0.f};

      for (int k0 = 0; k0 < DD; k0 += 64) {
#pragma unroll
        for (int j = 0; j < 2; ++j) {
          const int sub = wv * 2 + j;
          gload_lds16(inbf + (brow + sub * 8 + lr) * DD + k0 + lc * 8, &As[sub * 512]);
          gload_lds16(WxT  + ((long)(bcol + sub * 8 + lr)) * DD + k0 + lc * 8, &Bs[sub * 512]);
        }
        __syncthreads();
#pragma unroll
        for (int kk = 0; kk < 2; ++kk) {
          s16x8 af[4], bfx[2];
#pragma unroll
          for (int m = 0; m < 4; ++m)
            af[m] = *(const s16x8*)&As[(wr * 64 + m * 16 + cl) * 64 + kk * 32 + rg * 8];
#pragma unroll
          for (int n = 0; n < 2; ++n)
            bfx[n] = *(const s16x8*)&Bs[(wc * 32 + n * 16 + cl) * 64 + kk * 32 + rg * 8];
#pragma unroll
          for (int m = 0; m < 4; ++m)
#pragma unroll
            for (int n = 0; n < 2; ++n)
              acc[m][n] = __builtin_amdgcn_mfma_f32_16x16x32_bf16(af[m], bfx[n], acc[m][n], 0, 0, 0);
        }
        __syncthreads();
      }
#pragma unroll
      for (int n = 0; n < 2; ++n) {
        const int col = bcol + wc * 32 + n * 16 + cl;
        const float bv = biasp[col];
#pragma unroll
        for (int m = 0; m < 4; ++m)
#pragma unroll
          for (int j = 0; j < 4; ++j) {
            const long row = brow + wr * 64 + m * 16 + rg * 4 + j;
            st_short_sc1(&X[row * NG + col], f2bf(acc[m][n][j] + bv));
          }
      }
      asm volatile("s_waitcnt vmcnt(0)" ::: "memory");
      __syncthreads();
      if (tid == 0)
        __hip_atomic_fetch_add(&cnt[c * 32], 1u, __ATOMIC_RELAXED, __HIP_MEMORY_SCOPE_AGENT);
      __syncthreads();
    }

    // ---- heater: high-IPC FMA + junk MFMA; LDS-mirrored exit flag ----
    volatile u32* dflag = (volatile u32*)As;
    __syncthreads();
    if (tid == 0) *dflag = 0;
    __syncthreads();
    float x0 = 1.f + tid, x1 = 2.f, x2 = 3.f, x3 = 4.f, x4 = 5.f, x5 = 6.f, x6 = 7.f, x7 = 8.f;
    float y0 = 1.1f, y1 = 1.2f, y2 = 1.3f, y3 = 1.4f, y4 = 1.5f, y5 = 1.6f, y6 = 1.7f, y7 = 1.8f;
    const float m = 1.0000001f, c = 1.0e-7f;
    s16x8 jj = (s16x8){0x3f80, 0x3f80, 0x3f80, 0x3f80, 0x3f80, 0x3f80, 0x3f80, 0x3f80};
    f32x4 aj0 = (f32x4){0.f,0.f,0.f,0.f}, aj1 = (f32x4){0.f,0.f,0.f,0.f};
    int it2 = 0;
    for (;;) {
#pragma unroll
      for (int u = 0; u < 4; ++u) {
        x0 = __builtin_fmaf(x0, m, c); x1 = __builtin_fmaf(x1, m, c);
        x2 = __builtin_fmaf(x2, m, c); x3 = __builtin_fmaf(x3, m, c);
        x4 = __builtin_fmaf(x4, m, c); x5 = __builtin_fmaf(x5, m, c);
        x6 = __builtin_fmaf(x6, m, c); x7 = __builtin_fmaf(x7, m, c);
        y0 = __builtin_fmaf(y0, m, c); y1 = __builtin_fmaf(y1, m, c);
        y2 = __builtin_fmaf(y2, m, c); y3 = __builtin_fmaf(y3, m, c);
        y4 = __builtin_fmaf(y4, m, c); y5 = __builtin_fmaf(y5, m, c);
        y6 = __builtin_fmaf(y6, m, c); y7 = __builtin_fmaf(y7, m, c);
      }
      aj0 = __builtin_amdgcn_mfma_f32_16x16x32_bf16(jj, jj, aj0, 0, 0, 0);
      aj1 = __builtin_amdgcn_mfma_f32_16x16x32_bf16(jj, jj, aj1, 0, 0, 0);
      if ((++it2 & 31) == 0) {
        if (tid == 0) {
          if (__hip_atomic_load(&ctl[16], __ATOMIC_RELAXED, __HIP_MEMORY_SCOPE_AGENT) >= (u32)NTWG)
            *dflag = 1;
        }
        if (*dflag) break;
      }
    }
    asm volatile("" :: "v"(x0), "v"(x1), "v"(x2), "v"(x3), "v"(x4), "v"(x5), "v"(x6), "v"(x7));
    asm volatile("" :: "v"(y0), "v"(y1), "v"(y2), "v"(y3), "v"(aj0), "v"(aj1));
    return;
  }

  // ================= team / LSTM WGs =================
  if (tid == 0) {
    u32 x;
    asm volatile("s_getreg_b32 %0, hwreg(HW_REG_XCC_ID)" : "=s"(x));
    x &= 7u;
    u32 r = __hip_atomic_fetch_add(&ctl[x], 1u, __ATOMIC_RELAXED, __HIP_MEMORY_SCOPE_AGENT);
    u32 p = 0;
    if (r >= NSLOT)
      p = __hip_atomic_fetch_add(&ctl[8], 1u, __ATOMIC_RELAXED, __HIP_MEMORY_SCOPE_AGENT);
    __hip_atomic_fetch_add(&ctl[9], 1u, __ATOMIC_RELAXED, __HIP_MEMORY_SCOPE_AGENT);
    while (__hip_atomic_load(&ctl[9], __ATOMIC_RELAXED, __HIP_MEMORY_SCOPE_AGENT) < (u32)NTWG)
      __builtin_amdgcn_s_sleep(4);
    u32 c[8];
#pragma unroll
    for (int i = 0; i < 8; ++i)
      c[i] = __hip_atomic_load(&ctl[i], __ATOMIC_RELAXED, __HIP_MEMORY_SCOPE_AGENT);
    int team = -1, slot = 0;
    if (r < NSLOT) { team = (int)x; slot = (int)r; }
    else {
      u32 acc = 0;
      for (int tt = 0; tt < 8; ++tt) {
        u32 have = c[tt] < NSLOT ? c[tt] : NSLOT;
        u32 miss = NSLOT - have;
        if (team < 0 && p < acc + miss) { team = tt; slot = (int)(have + (p - acc)); }
        acc += miss;
      }
    }
    s_team = team; s_slot = slot;
    s_mixed = (team >= 0 && c[team] < NSLOT) ? 1 : 0;
  }
  __syncthreads();
  const int team = s_team, slot = s_slot, mixed = s_mixed;
  if (team < 0) return;

  const int cl = l & 15, rg = l >> 4;
  const int gcol0 = slot * 256 + wv * 32;

  s16x8 bfr[2][16];
#pragma unroll
  for (int nt = 0; nt < 2; ++nt)
#pragma unroll
    for (int ks = 0; ks < 16; ++ks)
      bfr[nt][ks] = *(const s16x8*)&WhT[(long)(gcol0 + nt * 16 + cl) * HH + ks * 32 + rg * 8];

  const int prow = tid >> 6;
  const int phl  = tid & 63;
  const int grow = team * 8 + prow;
  const int ghl  = slot * 64 + phl;

  float creg = 0.f;
  u32* myflag = &flags[(team * 8 + slot) * 32];

  for (int c = 0; c < NCHUNK; ++c) {
    if (tid == 0) {
      while (__hip_atomic_load(&cnt[c * 32], __ATOMIC_RELAXED, __HIP_MEMORY_SCOPE_AGENT) < (u32)TPC)
        __builtin_amdgcn_s_sleep(16);
    }
    __syncthreads();

    for (int t = c * CHUNK_STEPS; t < (c + 1) * CHUNK_STEPS; ++t) {
      u16x4 xv = *(const u16x4*)&X[((long)t * BB + grow) * NG + slot * 256 + phl * 4];

      if (t > 0) {                       // R4-proven tight agent poll
        if (wv == 0) {
          const u32 tgt = (u32)t;
          u32 vv; unsigned long long b;
          do {
            vv = (l < NSLOT)
               ? __hip_atomic_load(&flags[(team * 8 + l) * 32], __ATOMIC_RELAXED,
                                   __HIP_MEMORY_SCOPE_AGENT)
               : tgt;
            b = __ballot(vv >= tgt);
          } while (b != ~0ULL);
        }
        __syncthreads();
      }

      f32x4 a0a = (f32x4){0.f,0.f,0.f,0.f}, a0b = (f32x4){0.f,0.f,0.f,0.f};
      f32x4 a1a = (f32x4){0.f,0.f,0.f,0.f}, a1b = (f32x4){0.f,0.f,0.f,0.f};
      if (t > 0) {
        const u16* Hp = Hh + (long)(t - 1) * BB * HH;
        s16x8 af[16];
#pragma unroll
        for (int ks = 0; ks < 16; ++ks) af[ks] = (s16x8){0,0,0,0,0,0,0,0};
        if (cl < 8) {
#pragma unroll
          for (int ks = 0; ks < 16; ++ks)
            af[ks] = *(const s16x8*)&Hp[(team * 8 + cl) * HH + ks * 32 + rg * 8];
        }
#pragma unroll
        for (int ks = 0; ks < 16; ks += 2) {
          a0a = __builtin_amdgcn_mfma_f32_16x16x32_bf16(af[ks],     bfr[0][ks],     a0a, 0, 0, 0);
          a1a = __builtin_amdgcn_mfma_f32_16x16x32_bf16(af[ks],     bfr[1][ks],     a1a, 0, 0, 0);
          a0b = __builtin_amdgcn_mfma_f32_16x16x32_bf16(af[ks + 1], bfr[0][ks + 1], a0b, 0, 0, 0);
          a1b = __builtin_amdgcn_mfma_f32_16x16x32_bf16(af[ks + 1], bfr[1][ks + 1], a1b, 0, 0, 0);
        }
      }
      const f32x4 acc0 = a0a + a0b, acc1 = a1a + a1b;
      if (rg < 2) {
#pragma unroll
        for (int j = 0; j < 4; ++j) {
          pre[rg * 4 + j][wv * 32 + cl]      = acc0[j];
          pre[rg * 4 + j][wv * 32 + 16 + cl] = acc1[j];
        }
      }
      __syncthreads();

      f32x4 pv = *(const f32x4*)&pre[prow][phl * 4];
      const float pi = pv[0] + bf2f((u16)xv.x);
      const float pf = pv[1] + bf2f((u16)xv.y);
      const float po = pv[2] + bf2f((u16)xv.z);
      const float pc = pv[3] + bf2f((u16)xv.w);
      const float ig = sig_fast(pi);
      const float fg = sig_fast(pf);
      const float og = sig_fast(po);
      const float ct = tanh_fast(pc);
      creg = fg * creg + ig * ct;
      const float hv = og * tanh_fast(creg);
      const u16 hb = f2bf(hv);

      // all data stores first (drained together), flag store LAST
      dout[((long)t * BB + grow) * HH + ghl] = hv;
      if (t == TT - 1) {
        doutH[grow * HH + ghl] = hv;
        doutC[grow * HH + ghl] = creg;
      }
      u16* hdst = &Hh[((long)t * BB + grow) * HH + ghl];
      if (!mixed) *hdst = hb;
      else asm volatile("global_store_short %0, %1, off sc1"
                        :: "v"(hdst), "v"((u32)hb) : "memory");

      asm volatile("s_waitcnt vmcnt(0)" ::: "memory");
      __syncthreads();
      if (tid == 0) {
        if (!mixed) st_plain(myflag, (u32)(t + 1));
        else __hip_atomic_store(myflag, (u32)(t + 1), __ATOMIC_RELAXED,
                                __HIP_MEMORY_SCOPE_AGENT);
      }
    }
  }

  Cst[grow * HH + ghl] = creg;
  __syncthreads();
  if (tid == 0)
    __hip_atomic_fetch_add(&ctl[16], 1u, __ATOMIC_RELAXED, __HIP_MEMORY_SCOPE_AGENT);
}

// ---------------- host ----------------
extern "C" void kernel_launch(void* const* d_in, const int* in_sizes, int n_in,
                              void* d_out, int out_size, void* d_ws, size_t ws_size,
                              hipStream_t stream)
{
  const float* inputs = (const float*)d_in[0];
  const float* W_xi = (const float*)d_in[1];
  const float* W_hi = (const float*)d_in[2];
  const float* b_i  = (const float*)d_in[3];
  const float* W_xf = (const float*)d_in[4];
  const float* W_hf = (const float*)d_in[5];
  const float* b_f  = (const float*)d_in[6];
  const float* W_xo = (const float*)d_in[7];
  const float* W_ho = (const float*)d_in[8];
  const float* b_o  = (const float*)d_in[9];
  const float* W_xc = (const float*)d_in[10];
  const float* W_hc = (const float*)d_in[11];
  const float* b_c  = (const float*)d_in[12];
  float* out = (float*)d_out;
  char* ws = (char*)d_ws;

  size_t off = 0;
  auto walloc = [&](size_t sz) { size_t o = off; off = (off + sz + 255) & ~(size_t)255; return o; };
  const size_t o_inbf  = walloc((size_t)TT * BB * DD * 2);
  const size_t o_WxT   = walloc((size_t)NG * DD * 2);
  const size_t o_WhT   = walloc((size_t)NG * HH * 2);
  const size_t o_bias  = walloc((size_t)NG * 4);
  const size_t o_C     = walloc((size_t)BB * HH * 4);
  const size_t o_Hh    = walloc((size_t)TT * BB * HH * 2);
  const size_t o_ctl   = walloc(256);
  const size_t o_flags = walloc(8192);
  const size_t o_cnt   = walloc((size_t)NCHUNK * 32 * 4);
  const size_t o_X     = walloc((size_t)TT * BB * NG * 2);

  u16*   inbf  = (u16*)(ws + o_inbf);
  u16*   WxT   = (u16*)(ws + o_WxT);
  u16*   WhT   = (u16*)(ws + o_WhT);
  float* biasp = (float*)(ws + o_bias);
  u16*   Xbuf  = (u16*)(ws + o_X);
  u16*   Hh    = (u16*)(ws + o_Hh);
  float* Cst   = (float*)(ws + o_C);

  k_cast<<<dim3((TT * BB * DD) / 1024), dim3(256), 0, stream>>>(inputs, inbf, (long)TT * BB * DD);
  k_pack<<<dim3(DD), dim3(256), 0, stream>>>(W_xi, W_hi, b_i, W_xf, W_hf, b_f,
                                             W_xo, W_ho, b_o, W_xc, W_hc, b_c,
                                             WxT, WhT, biasp);

  float* doutH = out + (size_t)TT * BB * HH;
  float* doutC = doutH + (size_t)BB * HH;

  hipMemsetAsync(ws + o_ctl, 0, 256, stream);
  hipMemsetAsync(ws + o_flags, 0, 8192, stream);
  hipMemsetAsync(ws + o_cnt, 0, (size_t)NCHUNK * 32 * 4, stream);

  k_fused<<<dim3(NTWG + NGWG + 1), dim3(512), 0, stream>>>(
      inbf, WxT, WhT, biasp, Xbuf, Hh, Cst, out, doutH, doutC,
      (u32*)(ws + o_ctl), (u32*)(ws + o_flags), (u32*)(ws + o_cnt));
}

// Round 10
// 4375.524 us; speedup vs baseline: 538.0271x; 538.0271x over previous
//
#include <hip/hip_runtime.h>
#include <hip/hip_bf16.h>
#include <stdint.h>

// LSTM (T=1024, B=64, D=512, H=512) on gfx950.
// Phase 1: X[t,b,n] = inputs @ Wx (packed, bf16 MFMA), n = h*4 + gate.
// Phase 2: 8 teams of 8 WGs (XCD-local via HW_REG_XCC_ID election).
// R10 single-variable change vs R7: producer H-store and flag-stores use
//   sc0 (bypass L1 -> XCD L2) on the local-team path. Theory: CDNA4 vector
//   L1 is write-back; plain stores sit dirty in producer L1 ~µs before
//   remote visibility — the mechanism-independent 3.9µs/step plateau of
//   R4/R7/R8. Consumer: first-touch plain gen-flag poll + agent rescue
//   (deadlock-free under any semantics). Mixed teams: proven sc1 path.

typedef float    f32x4  __attribute__((ext_vector_type(4)));
typedef short    s16x8  __attribute__((ext_vector_type(8)));
typedef unsigned short u16;
typedef u16      u16x4  __attribute__((ext_vector_type(4)));
typedef unsigned int u32;

#define TT 1024
#define BB 64
#define DD 512
#define HH 512
#define NG 2048
#define NTEAM 8
#define NSLOT 8
#define NLW 128
#define NGEN 4

__device__ __forceinline__ u16 f2bf(float f) {
  __hip_bfloat16 h = __float2bfloat16(f);
  union { __hip_bfloat16 b; u16 u; } v; v.b = h; return v.u;
}
__device__ __forceinline__ float bf2f(u16 u) {
  union { unsigned int i; float f; } v; v.i = ((unsigned int)u) << 16; return v.f;
}
__device__ __forceinline__ float sig_fast(float x) { return 1.f / (1.f + __expf(-x)); }
__device__ __forceinline__ float tanh_fast(float x) { return 1.f - 2.f / (1.f + __expf(2.f * x)); }

__device__ __forceinline__ void gload_lds16(const u16* g, u16* l) {
  __builtin_amdgcn_global_load_lds(
      (const __attribute__((address_space(1))) unsigned int*)g,
      (__attribute__((address_space(3))) unsigned int*)l, 16, 0, 0);
}

__device__ __forceinline__ void st_plain(u32* p, u32 v) {
  asm volatile("global_store_dword %0, %1, off" :: "v"(p), "v"(v) : "memory");
}
// sc0 stores: bypass L1, land in XCD-shared L2 (remote-visible intra-XCD)
__device__ __forceinline__ void st_dword_sc0(u32* p, u32 v) {
  asm volatile("global_store_dword %0, %1, off sc0" :: "v"(p), "v"(v) : "memory");
}
__device__ __forceinline__ void st_short_sc0(u16* p, u16 v) {
  asm volatile("global_store_short %0, %1, off sc0" :: "v"(p), "v"((u32)v) : "memory");
}
__device__ __forceinline__ u32 ld_plain(const u32* p) {
  u32 v;
  asm volatile("global_load_dword %0, %1, off\n\ts_waitcnt vmcnt(0)"
               : "=v"(v) : "v"(p) : "memory");
  return v;
}

// ---------------- setup: cast inputs fp32 -> bf16 ----------------
__global__ void k_cast(const float* __restrict__ in, u16* __restrict__ out, long n) {
  long i = ((long)blockIdx.x * blockDim.x + threadIdx.x) * 4;
  if (i >= n) return;
  const float4 v = *(const float4*)(in + i);
  u16x4 o; o.x = f2bf(v.x); o.y = f2bf(v.y); o.z = f2bf(v.z); o.w = f2bf(v.w);
  *(u16x4*)(out + i) = o;
}

// ---------------- setup: pack weights ----------------
__global__ void k_pack(const float* __restrict__ Wxi, const float* __restrict__ Whi, const float* __restrict__ bi,
                       const float* __restrict__ Wxf, const float* __restrict__ Whf, const float* __restrict__ bfi,
                       const float* __restrict__ Wxo, const float* __restrict__ Who, const float* __restrict__ bo,
                       const float* __restrict__ Wxc, const float* __restrict__ Whc, const float* __restrict__ bc,
                       u16* __restrict__ WxT, u16* __restrict__ WhT, float* __restrict__ biasp)
{
  const int k = blockIdx.x;
  const float* Wx[4] = {Wxi, Wxf, Wxo, Wxc};
  const float* Wh[4] = {Whi, Whf, Who, Whc};
  for (int h = threadIdx.x; h < HH; h += blockDim.x) {
#pragma unroll
    for (int g = 0; g < 4; ++g) {
      const long n = h * 4 + g;
      WxT[n * DD + k] = f2bf(Wx[g][(long)k * HH + h]);
      WhT[n * HH + k] = f2bf(Wh[g][(long)k * HH + h]);
    }
  }
  if (k == 0) {
    const float* bp[4] = {bi, bfi, bo, bc};
    for (int n = threadIdx.x; n < NG; n += blockDim.x)
      biasp[n] = bp[n & 3][n >> 2];
  }
}

// ---------------- phase 1: X GEMM ----------------
__global__ __launch_bounds__(256) void k_gemm_x(
    const u16* __restrict__ A, const u16* __restrict__ BT,
    const float* __restrict__ biasp, u16* __restrict__ X)
{
  __shared__ __align__(16) u16 As[128 * 64];
  __shared__ __align__(16) u16 Bs[128 * 64];
  const int tid = threadIdx.x;
  const int l = tid & 63;
  const int w = tid >> 6;
  const int wr = w >> 1, wc = w & 1;
  const long brow = (long)blockIdx.y * 128;
  const int  bcol = blockIdx.x * 128;
  const int  lr = l >> 3, lc = l & 7;
  const int  cl = l & 15, rg = l >> 4;

  f32x4 acc[4][4];
#pragma unroll
  for (int m = 0; m < 4; ++m)
#pragma unroll
    for (int n = 0; n < 4; ++n) acc[m][n] = (f32x4){0.f, 0.f, 0.f, 0.f};

  for (int k0 = 0; k0 < DD; k0 += 64) {
#pragma unroll
    for (int j = 0; j < 4; ++j) {
      const int sub = w * 4 + j;
      gload_lds16(A  + (brow + sub * 8 + lr) * DD + k0 + lc * 8, &As[sub * 512]);
      gload_lds16(BT + ((long)(bcol + sub * 8 + lr)) * DD + k0 + lc * 8, &Bs[sub * 512]);
    }
    __syncthreads();
#pragma unroll
    for (int kk = 0; kk < 2; ++kk) {
      s16x8 af[4], bfr[4];
#pragma unroll
      for (int m = 0; m < 4; ++m)
        af[m] = *(const s16x8*)&As[(wr * 64 + m * 16 + cl) * 64 + kk * 32 + rg * 8];
#pragma unroll
      for (int n = 0; n < 4; ++n)
        bfr[n] = *(const s16x8*)&Bs[(wc * 64 + n * 16 + cl) * 64 + kk * 32 + rg * 8];
#pragma unroll
      for (int m = 0; m < 4; ++m)
#pragma unroll
        for (int n = 0; n < 4; ++n)
          acc[m][n] = __builtin_amdgcn_mfma_f32_16x16x32_bf16(af[m], bfr[n], acc[m][n], 0, 0, 0);
    }
    __syncthreads();
  }
#pragma unroll
  for (int n = 0; n < 4; ++n) {
    const int col = bcol + wc * 64 + n * 16 + cl;
    const float bv = biasp[col];
#pragma unroll
    for (int m = 0; m < 4; ++m)
#pragma unroll
      for (int j = 0; j < 4; ++j) {
        const long row = brow + wr * 64 + m * 16 + rg * 4 + j;
        X[row * NG + col] = f2bf(acc[m][n][j] + bv);
      }
  }
}

// ---------------- phase 2: team-local recurrent kernel ----------------
__global__ __launch_bounds__(512, 2) void k_lstm(
    const u16* __restrict__ X, const u16* __restrict__ WhT,
    u16* __restrict__ Hh, float* __restrict__ Cst,
    float* __restrict__ dout, float* __restrict__ doutH, float* __restrict__ doutC,
    u32* __restrict__ ctl, u32* __restrict__ flags, int t0, int t1)
{
  __shared__ __align__(16) float pre[8][260];
  __shared__ int s_team, s_slot, s_mixed;
  const int tid = threadIdx.x;

  // ---- adaptive team formation (placement-robust, deadlock-free) ----
  if (tid == 0) {
    u32 x;
    asm volatile("s_getreg_b32 %0, hwreg(HW_REG_XCC_ID)" : "=s"(x));
    x &= 7u;
    u32 r = __hip_atomic_fetch_add(&ctl[x], 1u, __ATOMIC_RELAXED, __HIP_MEMORY_SCOPE_AGENT);
    u32 p = 0;
    if (r >= NSLOT)
      p = __hip_atomic_fetch_add(&ctl[8], 1u, __ATOMIC_RELAXED, __HIP_MEMORY_SCOPE_AGENT);
    __hip_atomic_fetch_add(&ctl[9], 1u, __ATOMIC_RELAXED, __HIP_MEMORY_SCOPE_AGENT);
    while (__hip_atomic_load(&ctl[9], __ATOMIC_RELAXED, __HIP_MEMORY_SCOPE_AGENT) < (u32)NLW)
      __builtin_amdgcn_s_sleep(4);
    u32 c[8];
#pragma unroll
    for (int i = 0; i < 8; ++i)
      c[i] = __hip_atomic_load(&ctl[i], __ATOMIC_RELAXED, __HIP_MEMORY_SCOPE_AGENT);
    int team = -1, slot = 0;
    if (r < NSLOT) { team = (int)x; slot = (int)r; }
    else {
      u32 acc = 0;
      for (int tt = 0; tt < 8; ++tt) {
        u32 have = c[tt] < NSLOT ? c[tt] : NSLOT;
        u32 miss = NSLOT - have;
        if (team < 0 && p < acc + miss) { team = tt; slot = (int)(have + (p - acc)); }
        acc += miss;
      }
    }
    s_team = team; s_slot = slot;
    s_mixed = (team >= 0 && c[team] < NSLOT) ? 1 : 0;
  }
  __syncthreads();
  const int team = s_team, slot = s_slot, mixed = s_mixed;
  if (team < 0) return;

  const int l = tid & 63, wv = tid >> 6;
  const int cl = l & 15, rg = l >> 4;
  const int gcol0 = slot * 256 + wv * 32;

  s16x8 bfr[2][16];
#pragma unroll
  for (int nt = 0; nt < 2; ++nt)
#pragma unroll
    for (int ks = 0; ks < 16; ++ks)
      bfr[nt][ks] = *(const s16x8*)&WhT[(long)(gcol0 + nt * 16 + cl) * HH + ks * 32 + rg * 8];

  const int prow = tid >> 6;
  const int phl  = tid & 63;
  const int grow = team * 8 + prow;
  const int ghl  = slot * 64 + phl;

  float creg;
  if (t0 == 0) creg = 0.f; else creg = Cst[grow * HH + ghl];

  u32* fteam = flags + (long)team * TT * NGEN * 32;

  for (int t = t0; t < t1; ++t) {
    const int s = t - t0;
    u16x4 xv = *(const u16x4*)&X[((long)s * BB + grow) * NG + slot * 256 + phl * 4];

    if (t > t0) {
      if (wv == 0) {
        u32* fstep = fteam + (long)(s - 1) * NGEN * 32;
        u32 vv; unsigned long long b;
        int g = 0;
        for (;;) {
          if (l < NSLOT) vv = ld_plain(fstep + g * 32 + l);
          else vv = 1u;
          b = __ballot(vv != 0);
          if (b == ~0ULL) break;
          ++g;
          if (g >= NGEN) break;
          __builtin_amdgcn_s_sleep(2);
        }
        while (b != ~0ULL) {
          __builtin_amdgcn_s_sleep(8);
          if (l < NSLOT)
            vv = __hip_atomic_load(fstep + l, __ATOMIC_RELAXED, __HIP_MEMORY_SCOPE_AGENT);
          else vv = 1u;
          b = __ballot(vv != 0);
        }
      }
      __syncthreads();
    }

    f32x4 a0a = (f32x4){0.f,0.f,0.f,0.f}, a0b = (f32x4){0.f,0.f,0.f,0.f};
    f32x4 a1a = (f32x4){0.f,0.f,0.f,0.f}, a1b = (f32x4){0.f,0.f,0.f,0.f};
    if (t > 0) {
      const u16* Hp = Hh + (long)(t - 1) * BB * HH;
      s16x8 af[16];
#pragma unroll
      for (int ks = 0; ks < 16; ++ks) af[ks] = (s16x8){0,0,0,0,0,0,0,0};
      if (cl < 8) {
#pragma unroll
        for (int ks = 0; ks < 16; ++ks)
          af[ks] = *(const s16x8*)&Hp[(team * 8 + cl) * HH + ks * 32 + rg * 8];
      }
#pragma unroll
      for (int ks = 0; ks < 16; ks += 2) {
        a0a = __builtin_amdgcn_mfma_f32_16x16x32_bf16(af[ks],     bfr[0][ks],     a0a, 0, 0, 0);
        a1a = __builtin_amdgcn_mfma_f32_16x16x32_bf16(af[ks],     bfr[1][ks],     a1a, 0, 0, 0);
        a0b = __builtin_amdgcn_mfma_f32_16x16x32_bf16(af[ks + 1], bfr[0][ks + 1], a0b, 0, 0, 0);
        a1b = __builtin_amdgcn_mfma_f32_16x16x32_bf16(af[ks + 1], bfr[1][ks + 1], a1b, 0, 0, 0);
      }
    }
    const f32x4 acc0 = a0a + a0b, acc1 = a1a + a1b;
    if (rg < 2) {
#pragma unroll
      for (int j = 0; j < 4; ++j) {
        pre[rg * 4 + j][wv * 32 + cl]      = acc0[j];
        pre[rg * 4 + j][wv * 32 + 16 + cl] = acc1[j];
      }
    }
    __syncthreads();

    f32x4 pv = *(const f32x4*)&pre[prow][phl * 4];
    const float pi = pv[0] + bf2f((u16)xv.x);
    const float pf = pv[1] + bf2f((u16)xv.y);
    const float po = pv[2] + bf2f((u16)xv.z);
    const float pc = pv[3] + bf2f((u16)xv.w);
    const float ig = sig_fast(pi);
    const float fg = sig_fast(pf);
    const float og = sig_fast(po);
    const float ct = tanh_fast(pc);
    creg = fg * creg + ig * ct;
    const float hv = og * tanh_fast(creg);
    const u16 hb = f2bf(hv);
    u16* hdst = &Hh[((long)t * BB + grow) * HH + ghl];
    if (!mixed) st_short_sc0(hdst, hb);          // <-- sc0: bypass L1, land in L2
    else asm volatile("global_store_short %0, %1, off sc1"
                      :: "v"(hdst), "v"((u32)hb) : "memory");

    // drain H stores, then arrive on all NGEN generation lines
    asm volatile("s_waitcnt vmcnt(0)" ::: "memory");
    __syncthreads();
    if (tid == 0) {
      u32* fb = fteam + (long)s * NGEN * 32 + slot;
      if (!mixed) {
#pragma unroll
        for (int g = 0; g < NGEN; ++g) st_dword_sc0(fb + g * 32, 1u);  // <-- sc0
      } else {
#pragma unroll
        for (int g = 0; g < NGEN; ++g)
          __hip_atomic_store(fb + g * 32, 1u, __ATOMIC_RELAXED,
                             __HIP_MEMORY_SCOPE_AGENT);
      }
    }
    // dout off the critical path
    dout[((long)t * BB + grow) * HH + ghl] = hv;
    if (t == TT - 1) {
      doutH[grow * HH + ghl] = hv;
      doutC[grow * HH + ghl] = creg;
    }
  }

  Cst[grow * HH + ghl] = creg;
}

// ---------------- host ----------------
extern "C" void kernel_launch(void* const* d_in, const int* in_sizes, int n_in,
                              void* d_out, int out_size, void* d_ws, size_t ws_size,
                              hipStream_t stream)
{
  const float* inputs = (const float*)d_in[0];
  const float* W_xi = (const float*)d_in[1];
  const float* W_hi = (const float*)d_in[2];
  const float* b_i  = (const float*)d_in[3];
  const float* W_xf = (const float*)d_in[4];
  const float* W_hf = (const float*)d_in[5];
  const float* b_f  = (const float*)d_in[6];
  const float* W_xo = (const float*)d_in[7];
  const float* W_ho = (const float*)d_in[8];
  const float* b_o  = (const float*)d_in[9];
  const float* W_xc = (const float*)d_in[10];
  const float* W_hc = (const float*)d_in[11];
  const float* b_c  = (const float*)d_in[12];
  float* out = (float*)d_out;
  char* ws = (char*)d_ws;

  size_t off = 0;
  auto walloc = [&](size_t sz) { size_t o = off; off = (off + sz + 255) & ~(size_t)255; return o; };
  const size_t o_inbf  = walloc((size_t)TT * BB * DD * 2);
  const size_t o_WxT   = walloc((size_t)NG * DD * 2);
  const size_t o_WhT   = walloc((size_t)NG * HH * 2);
  const size_t o_bias  = walloc((size_t)NG * 4);
  const size_t o_C     = walloc((size_t)BB * HH * 4);
  const size_t o_Hh    = walloc((size_t)TT * BB * HH * 2);
  const size_t o_ctl   = walloc(256);
  const size_t flags_bytes = (size_t)NTEAM * TT * NGEN * 32 * 4;
  const size_t o_flags = walloc(flags_bytes);
  const size_t o_X     = off;

  const size_t bytes_per_step = (size_t)BB * NG * 2;
  long spc = (ws_size > o_X) ? (long)((ws_size - o_X) / bytes_per_step) : 0;
  if (spc > TT) spc = TT;
  spc &= ~1L;
  if (spc < 2) spc = 2;

  u16*   inbf  = (u16*)(ws + o_inbf);
  u16*   WxT   = (u16*)(ws + o_WxT);
  u16*   WhT   = (u16*)(ws + o_WhT);
  float* biasp = (float*)(ws + o_bias);
  u16*   Xbuf  = (u16*)(ws + o_X);
  u16*   Hh    = (u16*)(ws + o_Hh);
  float* Cst   = (float*)(ws + o_C);

  k_cast<<<dim3((TT * BB * DD) / 1024), dim3(256), 0, stream>>>(inputs, inbf, (long)TT * BB * DD);
  k_pack<<<dim3(DD), dim3(256), 0, stream>>>(W_xi, W_hi, b_i, W_xf, W_hf, b_f,
                                             W_xo, W_ho, b_o, W_xc, W_hc, b_c,
                                             WxT, WhT, biasp);

  float* doutH = out + (size_t)TT * BB * HH;
  float* doutC = doutH + (size_t)BB * HH;

  for (int t0 = 0; t0 < TT; t0 += (int)spc) {
    int t1 = t0 + (int)spc; if (t1 > TT) t1 = TT;
    const int rows = (t1 - t0) * BB;
    k_gemm_x<<<dim3(NG / 128, rows / 128), dim3(256), 0, stream>>>(
        inbf + (size_t)t0 * BB * DD, WxT, biasp, Xbuf);
    hipMemsetAsync(ws + o_ctl, 0, 256, stream);
    hipMemsetAsync(ws + o_flags, 0, flags_bytes, stream);
    k_lstm<<<dim3(NLW), dim3(512), 0, stream>>>(
        Xbuf, WhT, Hh, Cst, out, doutH, doutC,
        (u32*)(ws + o_ctl), (u32*)(ws + o_flags), t0, t1);
  }
}

// Round 11
// 4312.918 us; speedup vs baseline: 545.8370x; 1.0145x over previous
//
#include <hip/hip_runtime.h>
#include <hip/hip_bf16.h>
#include <stdint.h>

// LSTM (T=1024, B=64, D=512, H=512) on gfx950.
// Phase 1: X[t,b,n] = inputs @ Wx (packed, bf16 MFMA), n = h*4 + gate.
// Phase 2: 8 teams of 8 WGs (XCD-local via HW_REG_XCC_ID election).
// R11: poll-cost fix. R7's 4µs/step = each failed first-touch flag poll is
//   an HBM round trip (~900cy) that caches stale 0. Now: producers PREWARM
//   step s+1's gen lines with 0 during step s (L2-resident -> failed poll =
//   ~300cy L2 hit), 8 generations with exponential sleep spacing (~2.4µs
//   coverage), arrive-stores from 8 parallel lanes after a single vmcnt(0)
//   drain of all data stores, rescue via atomic fetch_add (RMW at L2/MALL).

typedef float    f32x4  __attribute__((ext_vector_type(4)));
typedef short    s16x8  __attribute__((ext_vector_type(8)));
typedef unsigned short u16;
typedef u16      u16x4  __attribute__((ext_vector_type(4)));
typedef unsigned int u32;

#define TT 1024
#define BB 64
#define DD 512
#define HH 512
#define NG 2048
#define NTEAM 8
#define NSLOT 8
#define NLW 128
#define NGEN 8

__device__ __forceinline__ u16 f2bf(float f) {
  __hip_bfloat16 h = __float2bfloat16(f);
  union { __hip_bfloat16 b; u16 u; } v; v.b = h; return v.u;
}
__device__ __forceinline__ float bf2f(u16 u) {
  union { unsigned int i; float f; } v; v.i = ((unsigned int)u) << 16; return v.f;
}
__device__ __forceinline__ float sig_fast(float x) { return 1.f / (1.f + __expf(-x)); }
__device__ __forceinline__ float tanh_fast(float x) { return 1.f - 2.f / (1.f + __expf(2.f * x)); }

__device__ __forceinline__ void gload_lds16(const u16* g, u16* l) {
  __builtin_amdgcn_global_load_lds(
      (const __attribute__((address_space(1))) unsigned int*)g,
      (__attribute__((address_space(3))) unsigned int*)l, 16, 0, 0);
}

__device__ __forceinline__ void st_plain(u32* p, u32 v) {
  asm volatile("global_store_dword %0, %1, off" :: "v"(p), "v"(v) : "memory");
}
__device__ __forceinline__ u32 ld_plain(const u32* p) {
  u32 v;
  asm volatile("global_load_dword %0, %1, off\n\ts_waitcnt vmcnt(0)"
               : "=v"(v) : "v"(p) : "memory");
  return v;
}

// ---------------- setup: cast inputs fp32 -> bf16 ----------------
__global__ void k_cast(const float* __restrict__ in, u16* __restrict__ out, long n) {
  long i = ((long)blockIdx.x * blockDim.x + threadIdx.x) * 4;
  if (i >= n) return;
  const float4 v = *(const float4*)(in + i);
  u16x4 o; o.x = f2bf(v.x); o.y = f2bf(v.y); o.z = f2bf(v.z); o.w = f2bf(v.w);
  *(u16x4*)(out + i) = o;
}

// ---------------- setup: pack weights ----------------
__global__ void k_pack(const float* __restrict__ Wxi, const float* __restrict__ Whi, const float* __restrict__ bi,
                       const float* __restrict__ Wxf, const float* __restrict__ Whf, const float* __restrict__ bfi,
                       const float* __restrict__ Wxo, const float* __restrict__ Who, const float* __restrict__ bo,
                       const float* __restrict__ Wxc, const float* __restrict__ Whc, const float* __restrict__ bc,
                       u16* __restrict__ WxT, u16* __restrict__ WhT, float* __restrict__ biasp)
{
  const int k = blockIdx.x;
  const float* Wx[4] = {Wxi, Wxf, Wxo, Wxc};
  const float* Wh[4] = {Whi, Whf, Who, Whc};
  for (int h = threadIdx.x; h < HH; h += blockDim.x) {
#pragma unroll
    for (int g = 0; g < 4; ++g) {
      const long n = h * 4 + g;
      WxT[n * DD + k] = f2bf(Wx[g][(long)k * HH + h]);
      WhT[n * HH + k] = f2bf(Wh[g][(long)k * HH + h]);
    }
  }
  if (k == 0) {
    const float* bp[4] = {bi, bfi, bo, bc};
    for (int n = threadIdx.x; n < NG; n += blockDim.x)
      biasp[n] = bp[n & 3][n >> 2];
  }
}

// ---------------- phase 1: X GEMM ----------------
__global__ __launch_bounds__(256) void k_gemm_x(
    const u16* __restrict__ A, const u16* __restrict__ BT,
    const float* __restrict__ biasp, u16* __restrict__ X)
{
  __shared__ __align__(16) u16 As[128 * 64];
  __shared__ __align__(16) u16 Bs[128 * 64];
  const int tid = threadIdx.x;
  const int l = tid & 63;
  const int w = tid >> 6;
  const int wr = w >> 1, wc = w & 1;
  const long brow = (long)blockIdx.y * 128;
  const int  bcol = blockIdx.x * 128;
  const int  lr = l >> 3, lc = l & 7;
  const int  cl = l & 15, rg = l >> 4;

  f32x4 acc[4][4];
#pragma unroll
  for (int m = 0; m < 4; ++m)
#pragma unroll
    for (int n = 0; n < 4; ++n) acc[m][n] = (f32x4){0.f, 0.f, 0.f, 0.f};

  for (int k0 = 0; k0 < DD; k0 += 64) {
#pragma unroll
    for (int j = 0; j < 4; ++j) {
      const int sub = w * 4 + j;
      gload_lds16(A  + (brow + sub * 8 + lr) * DD + k0 + lc * 8, &As[sub * 512]);
      gload_lds16(BT + ((long)(bcol + sub * 8 + lr)) * DD + k0 + lc * 8, &Bs[sub * 512]);
    }
    __syncthreads();
#pragma unroll
    for (int kk = 0; kk < 2; ++kk) {
      s16x8 af[4], bfr[4];
#pragma unroll
      for (int m = 0; m < 4; ++m)
        af[m] = *(const s16x8*)&As[(wr * 64 + m * 16 + cl) * 64 + kk * 32 + rg * 8];
#pragma unroll
      for (int n = 0; n < 4; ++n)
        bfr[n] = *(const s16x8*)&Bs[(wc * 64 + n * 16 + cl) * 64 + kk * 32 + rg * 8];
#pragma unroll
      for (int m = 0; m < 4; ++m)
#pragma unroll
        for (int n = 0; n < 4; ++n)
          acc[m][n] = __builtin_amdgcn_mfma_f32_16x16x32_bf16(af[m], bfr[n], acc[m][n], 0, 0, 0);
    }
    __syncthreads();
  }
#pragma unroll
  for (int n = 0; n < 4; ++n) {
    const int col = bcol + wc * 64 + n * 16 + cl;
    const float bv = biasp[col];
#pragma unroll
    for (int m = 0; m < 4; ++m)
#pragma unroll
      for (int j = 0; j < 4; ++j) {
        const long row = brow + wr * 64 + m * 16 + rg * 4 + j;
        X[row * NG + col] = f2bf(acc[m][n][j] + bv);
      }
  }
}

// ---------------- phase 2: team-local recurrent kernel ----------------
__global__ __launch_bounds__(512, 2) void k_lstm(
    const u16* __restrict__ X, const u16* __restrict__ WhT,
    u16* __restrict__ Hh, float* __restrict__ Cst,
    float* __restrict__ dout, float* __restrict__ doutH, float* __restrict__ doutC,
    u32* __restrict__ ctl, u32* __restrict__ flags, int t0, int t1)
{
  __shared__ __align__(16) float pre[8][260];
  __shared__ int s_team, s_slot, s_mixed;
  const int tid = threadIdx.x;

  // ---- adaptive team formation (placement-robust, deadlock-free) ----
  if (tid == 0) {
    u32 x;
    asm volatile("s_getreg_b32 %0, hwreg(HW_REG_XCC_ID)" : "=s"(x));
    x &= 7u;
    u32 r = __hip_atomic_fetch_add(&ctl[x], 1u, __ATOMIC_RELAXED, __HIP_MEMORY_SCOPE_AGENT);
    u32 p = 0;
    if (r >= NSLOT)
      p = __hip_atomic_fetch_add(&ctl[8], 1u, __ATOMIC_RELAXED, __HIP_MEMORY_SCOPE_AGENT);
    __hip_atomic_fetch_add(&ctl[9], 1u, __ATOMIC_RELAXED, __HIP_MEMORY_SCOPE_AGENT);
    while (__hip_atomic_load(&ctl[9], __ATOMIC_RELAXED, __HIP_MEMORY_SCOPE_AGENT) < (u32)NLW)
      __builtin_amdgcn_s_sleep(4);
    u32 c[8];
#pragma unroll
    for (int i = 0; i < 8; ++i)
      c[i] = __hip_atomic_load(&ctl[i], __ATOMIC_RELAXED, __HIP_MEMORY_SCOPE_AGENT);
    int team = -1, slot = 0;
    if (r < NSLOT) { team = (int)x; slot = (int)r; }
    else {
      u32 acc = 0;
      for (int tt = 0; tt < 8; ++tt) {
        u32 have = c[tt] < NSLOT ? c[tt] : NSLOT;
        u32 miss = NSLOT - have;
        if (team < 0 && p < acc + miss) { team = tt; slot = (int)(have + (p - acc)); }
        acc += miss;
      }
    }
    s_team = team; s_slot = slot;
    s_mixed = (team >= 0 && c[team] < NSLOT) ? 1 : 0;
  }
  __syncthreads();
  const int team = s_team, slot = s_slot, mixed = s_mixed;
  if (team < 0) return;

  const int l = tid & 63, wv = tid >> 6;
  const int cl = l & 15, rg = l >> 4;
  const int gcol0 = slot * 256 + wv * 32;

  s16x8 bfr[2][16];
#pragma unroll
  for (int nt = 0; nt < 2; ++nt)
#pragma unroll
    for (int ks = 0; ks < 16; ++ks)
      bfr[nt][ks] = *(const s16x8*)&WhT[(long)(gcol0 + nt * 16 + cl) * HH + ks * 32 + rg * 8];

  const int prow = tid >> 6;
  const int phl  = tid & 63;
  const int grow = team * 8 + prow;
  const int ghl  = slot * 64 + phl;

  float creg;
  if (t0 == 0) creg = 0.f; else creg = Cst[grow * HH + ghl];

  u32* fteam = flags + (long)team * TT * NGEN * 32;
  const int nsteps = t1 - t0;

  for (int t = t0; t < t1; ++t) {
    const int s = t - t0;
    u16x4 xv = *(const u16x4*)&X[((long)s * BB + grow) * NG + slot * 256 + phl * 4];

    if (t > t0) {
      if (wv == 0) {
        u32* fstep = fteam + (long)(s - 1) * NGEN * 32;
        int g = 0;
        auto touch = [&]() -> bool {
          u32 vv = (l < NSLOT) ? ld_plain(fstep + g * 32 + l) : 1u;
          unsigned long long b = __ballot(vv != 0);
          ++g;
          return b == ~0ULL;
        };
        bool ok = touch();                                  // gen 0
        if (!ok) { __builtin_amdgcn_s_sleep(1);  ok = touch(); }  // +64cy
        if (!ok) { __builtin_amdgcn_s_sleep(2);  ok = touch(); }  // +128
        if (!ok) { __builtin_amdgcn_s_sleep(4);  ok = touch(); }  // +256
        if (!ok) { __builtin_amdgcn_s_sleep(4);  ok = touch(); }  // +256
        if (!ok) { __builtin_amdgcn_s_sleep(8);  ok = touch(); }  // +512
        if (!ok) { __builtin_amdgcn_s_sleep(8);  ok = touch(); }  // +512
        if (!ok) { __builtin_amdgcn_s_sleep(16); ok = touch(); }  // +1024
        while (!ok) {                       // rescue: RMW executes at cache
          __builtin_amdgcn_s_sleep(8);
          u32 vv = (l < NSLOT)
            ? __hip_atomic_fetch_add(fstep + l, 0u, __ATOMIC_RELAXED,
                                     __HIP_MEMORY_SCOPE_AGENT)
            : 1u;
          ok = (__ballot(vv != 0) == ~0ULL);
        }
      }
      __syncthreads();
    }

    f32x4 a0a = (f32x4){0.f,0.f,0.f,0.f}, a0b = (f32x4){0.f,0.f,0.f,0.f};
    f32x4 a1a = (f32x4){0.f,0.f,0.f,0.f}, a1b = (f32x4){0.f,0.f,0.f,0.f};
    if (t > 0) {
      const u16* Hp = Hh + (long)(t - 1) * BB * HH;
      s16x8 af[16];
#pragma unroll
      for (int ks = 0; ks < 16; ++ks) af[ks] = (s16x8){0,0,0,0,0,0,0,0};
      if (cl < 8) {
#pragma unroll
        for (int ks = 0; ks < 16; ++ks)
          af[ks] = *(const s16x8*)&Hp[(team * 8 + cl) * HH + ks * 32 + rg * 8];
      }
#pragma unroll
      for (int ks = 0; ks < 16; ks += 2) {
        a0a = __builtin_amdgcn_mfma_f32_16x16x32_bf16(af[ks],     bfr[0][ks],     a0a, 0, 0, 0);
        a1a = __builtin_amdgcn_mfma_f32_16x16x32_bf16(af[ks],     bfr[1][ks],     a1a, 0, 0, 0);
        a0b = __builtin_amdgcn_mfma_f32_16x16x32_bf16(af[ks + 1], bfr[0][ks + 1], a0b, 0, 0, 0);
        a1b = __builtin_amdgcn_mfma_f32_16x16x32_bf16(af[ks + 1], bfr[1][ks + 1], a1b, 0, 0, 0);
      }
    }
    const f32x4 acc0 = a0a + a0b, acc1 = a1a + a1b;
    if (rg < 2) {
#pragma unroll
      for (int j = 0; j < 4; ++j) {
        pre[rg * 4 + j][wv * 32 + cl]      = acc0[j];
        pre[rg * 4 + j][wv * 32 + 16 + cl] = acc1[j];
      }
    }
    __syncthreads();

    f32x4 pv = *(const f32x4*)&pre[prow][phl * 4];
    const float pi = pv[0] + bf2f((u16)xv.x);
    const float pf = pv[1] + bf2f((u16)xv.y);
    const float po = pv[2] + bf2f((u16)xv.z);
    const float pc = pv[3] + bf2f((u16)xv.w);
    const float ig = sig_fast(pi);
    const float fg = sig_fast(pf);
    const float og = sig_fast(po);
    const float ct = tanh_fast(pc);
    creg = fg * creg + ig * ct;
    const float hv = og * tanh_fast(creg);
    const u16 hb = f2bf(hv);
    u16* hdst = &Hh[((long)t * BB + grow) * HH + ghl];
    if (!mixed) *hdst = hb;
    else asm volatile("global_store_short %0, %1, off sc1"
                      :: "v"(hdst), "v"((u32)hb) : "memory");

    // ALL data stores before one drain (dout included -> clean vmcnt at poll)
    dout[((long)t * BB + grow) * HH + ghl] = hv;
    if (t == TT - 1) {
      doutH[grow * HH + ghl] = hv;
      doutC[grow * HH + ghl] = creg;
    }
    asm volatile("s_waitcnt vmcnt(0)" ::: "memory");
    __syncthreads();

    // arrive: 8 gen lines in parallel lanes; prewarm next step's lines
    if (wv == 0 && l < NGEN) {
      u32* fb = fteam + (long)s * NGEN * 32 + l * 32 + slot;
      if (!mixed) st_plain(fb, 1u);
      else __hip_atomic_store(fb, 1u, __ATOMIC_RELAXED, __HIP_MEMORY_SCOPE_AGENT);
      if (s + 1 < nsteps)
        st_plain(fteam + (long)(s + 1) * NGEN * 32 + l * 32 + slot, 0u);
    }
  }

  Cst[grow * HH + ghl] = creg;
}

// ---------------- host ----------------
extern "C" void kernel_launch(void* const* d_in, const int* in_sizes, int n_in,
                              void* d_out, int out_size, void* d_ws, size_t ws_size,
                              hipStream_t stream)
{
  const float* inputs = (const float*)d_in[0];
  const float* W_xi = (const float*)d_in[1];
  const float* W_hi = (const float*)d_in[2];
  const float* b_i  = (const float*)d_in[3];
  const float* W_xf = (const float*)d_in[4];
  const float* W_hf = (const float*)d_in[5];
  const float* b_f  = (const float*)d_in[6];
  const float* W_xo = (const float*)d_in[7];
  const float* W_ho = (const float*)d_in[8];
  const float* b_o  = (const float*)d_in[9];
  const float* W_xc = (const float*)d_in[10];
  const float* W_hc = (const float*)d_in[11];
  const float* b_c  = (const float*)d_in[12];
  float* out = (float*)d_out;
  char* ws = (char*)d_ws;

  size_t off = 0;
  auto walloc = [&](size_t sz) { size_t o = off; off = (off + sz + 255) & ~(size_t)255; return o; };
  const size_t o_inbf  = walloc((size_t)TT * BB * DD * 2);
  const size_t o_WxT   = walloc((size_t)NG * DD * 2);
  const size_t o_WhT   = walloc((size_t)NG * HH * 2);
  const size_t o_bias  = walloc((size_t)NG * 4);
  const size_t o_C     = walloc((size_t)BB * HH * 4);
  const size_t o_Hh    = walloc((size_t)TT * BB * HH * 2);
  const size_t o_ctl   = walloc(256);
  const size_t flags_bytes = (size_t)NTEAM * TT * NGEN * 32 * 4;  // 8 MB
  const size_t o_flags = walloc(flags_bytes);
  const size_t o_X     = off;

  const size_t bytes_per_step = (size_t)BB * NG * 2;
  long spc = (ws_size > o_X) ? (long)((ws_size - o_X) / bytes_per_step) : 0;
  if (spc > TT) spc = TT;
  spc &= ~1L;
  if (spc < 2) spc = 2;

  u16*   inbf  = (u16*)(ws + o_inbf);
  u16*   WxT   = (u16*)(ws + o_WxT);
  u16*   WhT   = (u16*)(ws + o_WhT);
  float* biasp = (float*)(ws + o_bias);
  u16*   Xbuf  = (u16*)(ws + o_X);
  u16*   Hh    = (u16*)(ws + o_Hh);
  float* Cst   = (float*)(ws + o_C);

  k_cast<<<dim3((TT * BB * DD) / 1024), dim3(256), 0, stream>>>(inputs, inbf, (long)TT * BB * DD);
  k_pack<<<dim3(DD), dim3(256), 0, stream>>>(W_xi, W_hi, b_i, W_xf, W_hf, b_f,
                                             W_xo, W_ho, b_o, W_xc, W_hc, b_c,
                                             WxT, WhT, biasp);

  float* doutH = out + (size_t)TT * BB * HH;
  float* doutC = doutH + (size_t)BB * HH;

  for (int t0 = 0; t0 < TT; t0 += (int)spc) {
    int t1 = t0 + (int)spc; if (t1 > TT) t1 = TT;
    const int rows = (t1 - t0) * BB;
    k_gemm_x<<<dim3(NG / 128, rows / 128), dim3(256), 0, stream>>>(
        inbf + (size_t)t0 * BB * DD, WxT, biasp, Xbuf);
    hipMemsetAsync(ws + o_ctl, 0, 256, stream);
    hipMemsetAsync(ws + o_flags, 0, flags_bytes, stream);
    k_lstm<<<dim3(NLW), dim3(512), 0, stream>>>(
        Xbuf, WhT, Hh, Cst, out, doutH, doutC,
        (u32*)(ws + o_ctl), (u32*)(ws + o_flags), t0, t1);
  }
}